// Round 6
// baseline (329.459 us; speedup 1.0000x reference)
//
#include <hip/hip_runtime.h>

typedef unsigned short u16;
typedef short bf16x8 __attribute__((ext_vector_type(8)));
typedef float f32x4 __attribute__((ext_vector_type(4)));
typedef unsigned int u32x4 __attribute__((ext_vector_type(4)));
typedef unsigned short u16x4 __attribute__((ext_vector_type(4)));
typedef unsigned short u16x8 __attribute__((ext_vector_type(8)));

#define S_LEN 2048
#define NHEAD 16
#define NKV 8
#define HD 128

__device__ __forceinline__ u16 f2bf(float f) {
  unsigned u = __builtin_bit_cast(unsigned, f);
  u = (u + 0x7FFFu + ((u >> 16) & 1u)) >> 16;
  return (u16)u;
}
__device__ __forceinline__ float bf2f(u16 h) {
  unsigned u = ((unsigned)h) << 16;
  return __builtin_bit_cast(float, u);
}

__device__ __forceinline__ void gl_lds16(const void* g, void* l) {
  __builtin_amdgcn_global_load_lds(
      (const __attribute__((address_space(1))) unsigned int*)g,
      (__attribute__((address_space(3))) unsigned int*)l, 16, 0, 0);
}

__device__ __forceinline__ float redmax16(float v) {
  v = fmaxf(v, __shfl_xor(v, 1));
  v = fmaxf(v, __shfl_xor(v, 2));
  v = fmaxf(v, __shfl_xor(v, 4));
  v = fmaxf(v, __shfl_xor(v, 8));
  return v;
}

// ---------------- elementwise f32 -> bf16 ----------------
__global__ __launch_bounds__(256) void conv_bf16(const float* __restrict__ in,
                                                 u16* __restrict__ out, int n4) {
  int i = blockIdx.x * 256 + threadIdx.x;
  if (i >= n4) return;
  f32x4 v = *(const f32x4*)(in + (size_t)i * 4);
  u16x4 o;
#pragma unroll
  for (int j = 0; j < 4; ++j) o[j] = f2bf(v[j]);
  *(u16x4*)(out + (size_t)i * 4) = o;
}

// ---- fused transpose of wq/wk/wv/wo: f32 [K][N] -> bf16 [roff+n][2048] ----
__global__ __launch_bounds__(256) void transpose_w4(
    const float* __restrict__ wq, const float* __restrict__ wk,
    const float* __restrict__ wv, const float* __restrict__ wo,
    u16* __restrict__ wcatT, u16* __restrict__ woT) {
  __shared__ float tile[64][65];
  int id = blockIdx.x;
  const float* in;
  u16* out;
  int N, roff, nx;
  if (id < 1024) {
    in = wq; out = wcatT; N = 2048; roff = 0; nx = 32;
  } else if (id < 1536) {
    in = wk; out = wcatT; N = 1024; roff = 2048; nx = 16; id -= 1024;
  } else if (id < 2048) {
    in = wv; out = wcatT; N = 1024; roff = 3072; nx = 16; id -= 1536;
  } else {
    in = wo; out = woT; N = 2048; roff = 0; nx = 32; id -= 2048;
  }
  int bx = id % nx;
  int by = id / nx;
  int k0 = by * 64, n0 = bx * 64;
  int tx = threadIdx.x & 63, ty = threadIdx.x >> 6;
#pragma unroll
  for (int p = 0; p < 16; ++p) {
    int r = p * 4 + ty;
    tile[r][tx] = in[(size_t)(k0 + r) * N + n0 + tx];
  }
  __syncthreads();
#pragma unroll
  for (int p = 0; p < 16; ++p) {
    int r = p * 4 + ty;
    out[(size_t)(roff + n0 + r) * 2048 + k0 + tx] = f2bf(tile[tx][r]);
  }
}

// ---------------- RoPE in-place on Q (scaled) and K ----------------
__global__ __launch_bounds__(256) void rope_qk(u16* __restrict__ q, u16* __restrict__ k,
                                               const float* __restrict__ fc,
                                               const float* __restrict__ fs) {
  const int QC = 2 * NHEAD * S_LEN * HD / 8;
  const int KC = 2 * NKV * S_LEN * HD / 8;
  int i = blockIdx.x * 256 + threadIdx.x;
  if (i >= QC + KC) return;
  u16* base;
  float scale;
  size_t e;
  if (i < QC) {
    base = q;
    e = (size_t)i * 8;
    scale = 0.12751744540368598f;  // log2(e)/sqrt(128)
  } else {
    base = k;
    e = (size_t)(i - QC) * 8;
    scale = 1.0f;
  }
  int d8 = (int)(e & 127);
  int s = (int)((e >> 7) & (S_LEN - 1));
  int dp0 = d8 >> 1;
  u16x8 v = *(const u16x8*)(base + e);
  u16x8 o;
#pragma unroll
  for (int p = 0; p < 4; ++p) {
    float xr = bf2f(v[2 * p]), xi = bf2f(v[2 * p + 1]);
    float c = fc[s * 64 + dp0 + p], sn = fs[s * 64 + dp0 + p];
    o[2 * p] = f2bf((xr * c - xi * sn) * scale);
    o[2 * p + 1] = f2bf((xr * sn + xi * c) * scale);
  }
  *(u16x8*)(base + e) = o;
}

// ===== ring-3 deep-pipelined GEMM: 128x256 tile, BK=64, counted vmcnt, =====
template <int EPI>
__global__ __launch_bounds__(512, 1) void gemm3r(
    const u16* __restrict__ A, const u16* __restrict__ Bt, float* __restrict__ Cf,
    u16* __restrict__ Qo, u16* __restrict__ Ko, u16* __restrict__ Vo, int N, int ntn) {
  constexpr int K = 2048, NT = K / 64;
  constexpr int BSZ = (128 + 256) * 64;
  __shared__ __align__(16) u16 lds[3][BSZ];

  const int t = threadIdx.x;
  const int l = t & 63, lh = l >> 4, ll = l & 15;
  const int w = t >> 6, wm = w >> 2, wn = w & 3;

  const int bid = blockIdx.x;
  const int swz = (bid & 7) * (gridDim.x >> 3) + (bid >> 3);
  const int tm = swz / ntn, tn = swz % ntn;

  const u16* Ab = A + (size_t)tm * 128 * K;
  const u16* Bb = Bt + (size_t)tn * 256 * K;

  const int sr = t >> 3;
  const int sc8 = ((t & 7) ^ (sr & 7)) * 8;

  f32x4 acc[4][4] = {};

  auto STAGE = [&](int tau) {
    const int kt = tau * 64;
    u16* buf = &lds[tau % 3][0];
#pragma unroll
    for (int c = 0; c < 2; ++c)
      gl_lds16(Ab + (size_t)(c * 64 + sr) * K + kt + sc8, buf + c * 4096 + t * 8);
#pragma unroll
    for (int c = 0; c < 4; ++c)
      gl_lds16(Bb + (size_t)(c * 64 + sr) * K + kt + sc8,
               buf + 8192 + c * 4096 + t * 8);
  };

  STAGE(0);
  STAGE(1);
  __builtin_amdgcn_s_waitcnt(0xF70 | 6);
  __builtin_amdgcn_s_barrier();
  asm volatile("" ::: "memory");

  for (int tt = 0; tt < NT; ++tt) {
    if (tt + 2 < NT) STAGE(tt + 2);
    const u16* bufA = &lds[tt % 3][0];
    const u16* bufB = bufA + 8192;
#pragma unroll
    for (int kk = 0; kk < 2; ++kk) {
      const int cb = ((kk * 4 + lh) ^ (ll & 7)) * 8;
      bf16x8 af[4], bv[4];
#pragma unroll
      for (int m = 0; m < 4; ++m)
        af[m] = *(const bf16x8*)(bufA + (wm * 64 + m * 16 + ll) * 64 + cb);
#pragma unroll
      for (int n = 0; n < 4; ++n)
        bv[n] = *(const bf16x8*)(bufB + (wn * 64 + n * 16 + ll) * 64 + cb);
      __builtin_amdgcn_s_setprio(1);
#pragma unroll
      for (int m = 0; m < 4; ++m)
#pragma unroll
        for (int n = 0; n < 4; ++n)
          acc[m][n] =
              __builtin_amdgcn_mfma_f32_16x16x32_bf16(af[m], bv[n], acc[m][n], 0, 0, 0);
      __builtin_amdgcn_s_setprio(0);
    }
    if (tt + 1 < NT) {
      if (tt + 2 < NT)
        __builtin_amdgcn_s_waitcnt(0xF70 | 6);
      else
        __builtin_amdgcn_s_waitcnt(0xF70);
      __builtin_amdgcn_s_barrier();
      asm volatile("" ::: "memory");
    }
  }

#pragma unroll
  for (int m = 0; m < 4; ++m)
#pragma unroll
    for (int n = 0; n < 4; ++n)
#pragma unroll
      for (int j = 0; j < 4; ++j) {
        int row = tm * 128 + wm * 64 + m * 16 + lh * 4 + j;
        int col = tn * 256 + wn * 64 + n * 16 + ll;
        if constexpr (EPI == 0) {
          Cf[(size_t)row * N + col] = acc[m][n][j];
        } else {
          int b = row >> 11, s = row & (S_LEN - 1);
          u16 val = f2bf(acc[m][n][j]);
          int d = col & 127;
          if (col < 2048) {
            int hh = col >> 7;
            Qo[(((size_t)b * NHEAD + hh) * S_LEN + s) * HD + d] = val;
          } else if (col < 3072) {
            int kh = (col >> 7) & 7;
            Ko[(((size_t)b * NKV + kh) * S_LEN + s) * HD + d] = val;
          } else {
            int kh = (col >> 7) & 7;
            Vo[(((size_t)b * NKV + kh) * S_LEN + s) * HD + d] = val;
          }
        }
      }
}

// ---- V [bkv][2048][128] -> Vt [bkv][128][2048] (LDS tiled transpose) ----
__global__ __launch_bounds__(256) void transpose_v(const u16* __restrict__ V,
                                                   u16* __restrict__ Vt) {
  __shared__ u16 tile[64][72];
  int id = blockIdx.x;
  int bkv = id >> 6;
  int dt = (id >> 5) & 1;
  int st = id & 31;
  const u16* Vb = V + (size_t)bkv * S_LEN * HD;
  u16* Vo = Vt + (size_t)bkv * HD * S_LEN;
  int r = threadIdx.x >> 3, c8 = (threadIdx.x & 7) * 8;
#pragma unroll
  for (int it = 0; it < 2; ++it) {
    int rr = it * 32 + r;
    *(u16x8*)(&tile[rr][c8]) =
        *(const u16x8*)(Vb + (size_t)(st * 64 + rr) * HD + dt * 64 + c8);
  }
  __syncthreads();
#pragma unroll
  for (int it = 0; it < 2; ++it) {
    int rr = it * 32 + r;
    u16x8 o;
#pragma unroll
    for (int j = 0; j < 8; ++j) o[j] = tile[c8 + j][rr];
    *(u16x8*)(Vo + (size_t)(dt * 64 + rr) * S_LEN + st * 64 + c8) = o;
  }
}

// ======= causal GQA flash attention: 8 waves, in-block KV split =======
// waves 0-3 (half 0): even KV tiles; waves 4-7 (half 1): odd KV tiles.
// Per-half unpadded XOR-swizzled K/V LDS (zero-conflict b128 reads).
// Flash-merge of the two halves through LDS at the end; half 0 writes O.
__global__ __launch_bounds__(512, 4) void attn_fwd(const u16* __restrict__ Q,
                                                   const u16* __restrict__ Kh,
                                                   const u16* __restrict__ Vt,
                                                   u16* __restrict__ O) {
  __shared__ __align__(16) u16 SH[40960];  // 80 KB

  const int t = threadIdx.x;
  const int w = t >> 6, l = t & 63, lh = l >> 4, ll = l & 15;
  const int qg = w & 3, half = w >> 2;
  const int t256 = t & 255;

  const int bid = blockIdx.x;
  const int swzb = (bid & 7) * 64 + (bid >> 3);
  const int bh = swzb >> 4;
  const int pair = swzb & 15;
  const int b = bh >> 4, h = bh & 15;
  const int bkv = b * NKV + (h >> 1);

  const u16* Qb = Q + (size_t)bh * S_LEN * HD;
  const u16* Kb = Kh + (size_t)bkv * S_LEN * HD;
  const u16* Vb = Vt + (size_t)bkv * HD * S_LEN;

  u16* KS = SH + half * 8192;           // [64 rows][128 u16] swizzled
  u16* VS = SH + 16384 + half * 8192;   // [128 rows][64 u16] swizzled
  u16* PW = SH + 32768 + w * 1024;      // per-wave P tile
  float* CmbO = (float*)SH;             // [4][16][128] f32 (aliases KS)
  float* CmbML = (float*)(SH + 16384);  // [4][2][16] f32 (aliases VS)

  const int krow = t256 >> 4;            // 0..15
  const int ksHi = t256 & 8, ksLo = t256 & 7;
  const int vrow = t256 >> 3;            // 0..31
  const int vsLo = t256 & 7;

  u16x8 krg[4], vrg[4];
  auto loadK = [&](int tile) {
    const int kv0 = tile * 64;
#pragma unroll
    for (int p = 0; p < 4; ++p) {
      int r = p * 16 + krow;
      int s = ksHi | (ksLo ^ (r & 7));  // pre-permuted source slot
      krg[p] = *(const u16x8*)(Kb + (size_t)(kv0 + r) * HD + s * 8);
    }
  };
  auto loadV = [&](int tile) {
    const int kv0 = tile * 64;
#pragma unroll
    for (int i = 0; i < 4; ++i) {
      int d = i * 32 + vrow;
      int s = vsLo ^ (d & 7);
      vrg[i] = *(const u16x8*)(Vb + (size_t)d * S_LEN + kv0 + s * 8);
    }
  };
  auto storeKV = [&]() {  // LDS writes linear in lane -> conflict-free
#pragma unroll
    for (int p = 0; p < 4; ++p)
      *(u16x8*)(KS + (p * 16 + krow) * 128 + (t256 & 15) * 8) = krg[p];
#pragma unroll
    for (int i = 0; i < 4; ++i)
      *(u16x8*)(VS + (i * 32 + vrow) * 64 + vsLo * 8) = vrg[i];
  };

  const bf16x8 vones = {0x3F80, 0x3F80, 0x3F80, 0x3F80, 0x3F80, 0x3F80, 0x3F80, 0x3F80};

  for (int hf = 0; hf < 2; ++hf) {
    const int qt = hf ? (31 - pair) : pair;
    const int q0 = qt * 64;

    bf16x8 qf[4];
#pragma unroll
    for (int c = 0; c < 4; ++c)
      qf[c] = *(const bf16x8*)(Qb + (size_t)(q0 + qg * 16 + ll) * HD + c * 32 + lh * 8);

    f32x4 accO[8] = {};
    f32x4 accL = {0.f, 0.f, 0.f, 0.f};
    float mrow[4] = {-1e30f, -1e30f, -1e30f, -1e30f};

    const int nt = qt + 1;
    const int nt2 = (nt + 1) >> 1;
    int ti = half;
    if (ti < nt) {
      loadK(ti);
      loadV(ti);
    }
    __syncthreads();  // also protects CmbO readers of previous hf
    if (ti < nt) storeKV();
    __syncthreads();

    for (int i = 0; i < nt2; ++i) {
      const int tin = ti + 2;
      const bool act = ti < nt;    // wave-uniform
      const bool actn = tin < nt;  // wave-uniform
      if (actn) loadK(tin);

      f32x4 sf[4];
      if (act) {
#pragma unroll
        for (int f = 0; f < 4; ++f) {
          sf[f] = f32x4{0.f, 0.f, 0.f, 0.f};
#pragma unroll
          for (int c = 0; c < 4; ++c) {
            const int slot = c * 4 + lh;
            const int eff = (slot & 8) | ((slot & 7) ^ (ll & 7));
            bf16x8 kf = *(const bf16x8*)(KS + (f * 16 + ll) * 128 + eff * 8);
            sf[f] = __builtin_amdgcn_mfma_f32_16x16x32_bf16(qf[c], kf, sf[f], 0, 0, 0);
          }
        }
        if (ti == nt - 1) {  // diagonal tile: causal mask
          const int kv0 = ti * 64;
#pragma unroll
          for (int f = 0; f < 4; ++f)
#pragma unroll
            for (int j = 0; j < 4; ++j) {
              int kvg = kv0 + f * 16 + ll;
              int qgl = q0 + qg * 16 + lh * 4 + j;
              if (kvg > qgl) sf[f][j] = -1e30f;
            }
        }
      }
      if (actn) loadV(tin);
      if (act) {
        float corr[4];
#pragma unroll
        for (int j = 0; j < 4; ++j) {
          float mx = fmaxf(fmaxf(sf[0][j], sf[1][j]), fmaxf(sf[2][j], sf[3][j]));
          mx = redmax16(mx);
          float mnew = fmaxf(mrow[j], mx);
          corr[j] = __builtin_amdgcn_exp2f(mrow[j] - mnew);
          mrow[j] = mnew;
#pragma unroll
          for (int f = 0; f < 4; ++f) sf[f][j] = __builtin_amdgcn_exp2f(sf[f][j] - mnew);
        }
#pragma unroll
        for (int n = 0; n < 8; ++n)
#pragma unroll
          for (int j = 0; j < 4; ++j) accO[n][j] *= corr[j];
#pragma unroll
        for (int j = 0; j < 4; ++j) accL[j] *= corr[j];

        char* Pw = (char*)PW;
#pragma unroll
        for (int f = 0; f < 4; ++f)
#pragma unroll
          for (int j = 0; j < 4; ++j) {
            int rr = lh * 4 + j, cc = f * 16 + ll;
            unsigned bo = (unsigned)(rr * 128 + cc * 2) ^ (unsigned)((rr & 7) << 4);
            *(u16*)(Pw + bo) = f2bf(sf[f][j]);
          }

#pragma unroll
        for (int kc = 0; kc < 2; ++kc) {
          unsigned bo =
              (unsigned)(ll * 128 + (kc * 32 + lh * 8) * 2) ^ (unsigned)((ll & 7) << 4);
          bf16x8 pf = *(const bf16x8*)(Pw + bo);
#pragma unroll
          for (int n = 0; n < 8; ++n) {
            const int eff = (kc * 4 + lh) ^ (ll & 7);
            bf16x8 vf = *(const bf16x8*)(VS + (n * 16 + ll) * 64 + eff * 8);
            accO[n] = __builtin_amdgcn_mfma_f32_16x16x32_bf16(pf, vf, accO[n], 0, 0, 0);
          }
          accL = __builtin_amdgcn_mfma_f32_16x16x32_bf16(pf, vones, accL, 0, 0, 0);
        }
      }
      __syncthreads();
      if (actn) storeKV();
      __syncthreads();
      ti = tin;
    }

    // ---- flash-merge of the two halves ----
    if (half == 1) {
#pragma unroll
      for (int n = 0; n < 8; ++n)
#pragma unroll
        for (int j = 0; j < 4; ++j)
          CmbO[(qg * 16 + lh * 4 + j) * 128 + n * 16 + ll] = accO[n][j];
      if (ll == 0) {
#pragma unroll
        for (int j = 0; j < 4; ++j) {
          CmbML[qg * 32 + lh * 4 + j] = mrow[j];
          CmbML[qg * 32 + 16 + lh * 4 + j] = accL[j];
        }
      }
    }
    __syncthreads();
    if (half == 0) {
      float aa[4], bb[4], inv[4];
#pragma unroll
      for (int j = 0; j < 4; ++j) {
        float m2 = CmbML[qg * 32 + lh * 4 + j];
        float l2 = CmbML[qg * 32 + 16 + lh * 4 + j];
        float mf = fmaxf(mrow[j], m2);
        aa[j] = __builtin_amdgcn_exp2f(mrow[j] - mf);
        bb[j] = __builtin_amdgcn_exp2f(m2 - mf);
        inv[j] = 1.0f / (accL[j] * aa[j] + l2 * bb[j]);
      }
      const size_t orow = (size_t)(b * S_LEN + q0 + qg * 16 + lh * 4) * 2048 + h * HD;
#pragma unroll
      for (int n = 0; n < 8; ++n)
#pragma unroll
        for (int j = 0; j < 4; ++j) {
          float o2 = CmbO[(qg * 16 + lh * 4 + j) * 128 + n * 16 + ll];
          O[orow + (size_t)j * 2048 + n * 16 + ll] =
              f2bf((accO[n][j] * aa[j] + o2 * bb[j]) * inv[j]);
        }
    }
  }
}

extern "C" void kernel_launch(void* const* d_in, const int* in_sizes, int n_in,
                              void* d_out, int out_size, void* d_ws, size_t ws_size,
                              hipStream_t stream) {
  (void)in_sizes;
  (void)n_in;
  (void)out_size;
  (void)ws_size;
  const float* x = (const float*)d_in[0];
  const float* fc = (const float*)d_in[1];
  const float* fs = (const float*)d_in[2];
  const float* wq = (const float*)d_in[3];
  const float* wk = (const float*)d_in[4];
  const float* wv = (const float*)d_in[5];
  const float* wo = (const float*)d_in[6];
  float* out = (float*)d_out;

  char* ws = (char*)d_ws;
  u16* wcatT = (u16*)ws;             // [4096][2048] bf16  16.78 MB (dead after gemm<1>)
  u16* vtb = (u16*)ws;               // aliases wcatT: [16][128][2048]  8.39 MB
  u16* woT = (u16*)(ws + 16777216);  // [2048][2048]        8.39 MB
  u16* xo = (u16*)(ws + 25165824);   // x_bf16 then O      16.78 MB
  u16* qb = (u16*)(ws + 41943040);   // [32][2048][128]    16.78 MB
  u16* kb = (u16*)(ws + 58720256);   // [16][2048][128]     8.39 MB
  u16* vb = (u16*)(ws + 67108864);   // [16][2048][128]     8.39 MB
  // total 75,497,472 bytes

  conv_bf16<<<8192, 256, 0, stream>>>(x, xo, 2097152);
  transpose_w4<<<3072, 256, 0, stream>>>(wq, wk, wv, wo, wcatT, woT);

  gemm3r<1><<<512, 512, 0, stream>>>(xo, wcatT, nullptr, qb, kb, vb, 4096, 16);
  transpose_v<<<1024, 256, 0, stream>>>(vb, vtb);
  rope_qk<<<6144, 256, 0, stream>>>(qb, kb, fc, fs);
  attn_fwd<<<512, 512, 0, stream>>>(qb, kb, vtb, xo);
  gemm3r<0><<<256, 512, 0, stream>>>(xo, woT, out, nullptr, nullptr, nullptr, 2048, 8);
}

// Round 7
// 234.170 us; speedup vs baseline: 1.4069x; 1.4069x over previous
//
#include <hip/hip_runtime.h>

typedef unsigned short u16;
typedef short bf16x8 __attribute__((ext_vector_type(8)));
typedef float f32x4 __attribute__((ext_vector_type(4)));
typedef unsigned int u32x4 __attribute__((ext_vector_type(4)));
typedef unsigned short u16x4 __attribute__((ext_vector_type(4)));
typedef unsigned short u16x8 __attribute__((ext_vector_type(8)));

#define S_LEN 2048
#define NHEAD 16
#define NKV 8
#define HD 128

__device__ __forceinline__ u16 f2bf(float f) {
  unsigned u = __builtin_bit_cast(unsigned, f);
  u = (u + 0x7FFFu + ((u >> 16) & 1u)) >> 16;
  return (u16)u;
}
__device__ __forceinline__ float bf2f(u16 h) {
  unsigned u = ((unsigned)h) << 16;
  return __builtin_bit_cast(float, u);
}

__device__ __forceinline__ void gl_lds16(const void* g, void* l) {
  __builtin_amdgcn_global_load_lds(
      (const __attribute__((address_space(1))) unsigned int*)g,
      (__attribute__((address_space(3))) unsigned int*)l, 16, 0, 0);
}

__device__ __forceinline__ float redmax16(float v) {
  v = fmaxf(v, __shfl_xor(v, 1));
  v = fmaxf(v, __shfl_xor(v, 2));
  v = fmaxf(v, __shfl_xor(v, 4));
  v = fmaxf(v, __shfl_xor(v, 8));
  return v;
}

// ---------------- elementwise f32 -> bf16 ----------------
__global__ __launch_bounds__(256) void conv_bf16(const float* __restrict__ in,
                                                 u16* __restrict__ out, int n4) {
  int i = blockIdx.x * 256 + threadIdx.x;
  if (i >= n4) return;
  f32x4 v = *(const f32x4*)(in + (size_t)i * 4);
  u16x4 o;
#pragma unroll
  for (int j = 0; j < 4; ++j) o[j] = f2bf(v[j]);
  *(u16x4*)(out + (size_t)i * 4) = o;
}

// ---- fused transpose of wq/wk/wv/wo: f32 [K][N] -> bf16 [roff+n][2048] ----
__global__ __launch_bounds__(256) void transpose_w4(
    const float* __restrict__ wq, const float* __restrict__ wk,
    const float* __restrict__ wv, const float* __restrict__ wo,
    u16* __restrict__ wcatT, u16* __restrict__ woT) {
  __shared__ float tile[64][65];
  int id = blockIdx.x;
  const float* in;
  u16* out;
  int N, roff, nx;
  if (id < 1024) {
    in = wq; out = wcatT; N = 2048; roff = 0; nx = 32;
  } else if (id < 1536) {
    in = wk; out = wcatT; N = 1024; roff = 2048; nx = 16; id -= 1024;
  } else if (id < 2048) {
    in = wv; out = wcatT; N = 1024; roff = 3072; nx = 16; id -= 1536;
  } else {
    in = wo; out = woT; N = 2048; roff = 0; nx = 32; id -= 2048;
  }
  int bx = id % nx;
  int by = id / nx;
  int k0 = by * 64, n0 = bx * 64;
  int tx = threadIdx.x & 63, ty = threadIdx.x >> 6;
#pragma unroll
  for (int p = 0; p < 16; ++p) {
    int r = p * 4 + ty;
    tile[r][tx] = in[(size_t)(k0 + r) * N + n0 + tx];
  }
  __syncthreads();
#pragma unroll
  for (int p = 0; p < 16; ++p) {
    int r = p * 4 + ty;
    out[(size_t)(roff + n0 + r) * 2048 + k0 + tx] = f2bf(tile[tx][r]);
  }
}

// ---------------- RoPE in-place on Q (scaled) and K ----------------
__global__ __launch_bounds__(256) void rope_qk(u16* __restrict__ q, u16* __restrict__ k,
                                               const float* __restrict__ fc,
                                               const float* __restrict__ fs) {
  const int QC = 2 * NHEAD * S_LEN * HD / 8;
  const int KC = 2 * NKV * S_LEN * HD / 8;
  int i = blockIdx.x * 256 + threadIdx.x;
  if (i >= QC + KC) return;
  u16* base;
  float scale;
  size_t e;
  if (i < QC) {
    base = q;
    e = (size_t)i * 8;
    scale = 0.12751744540368598f;  // log2(e)/sqrt(128)
  } else {
    base = k;
    e = (size_t)(i - QC) * 8;
    scale = 1.0f;
  }
  int d8 = (int)(e & 127);
  int s = (int)((e >> 7) & (S_LEN - 1));
  int dp0 = d8 >> 1;
  u16x8 v = *(const u16x8*)(base + e);
  u16x8 o;
#pragma unroll
  for (int p = 0; p < 4; ++p) {
    float xr = bf2f(v[2 * p]), xi = bf2f(v[2 * p + 1]);
    float c = fc[s * 64 + dp0 + p], sn = fs[s * 64 + dp0 + p];
    o[2 * p] = f2bf((xr * c - xi * sn) * scale);
    o[2 * p + 1] = f2bf((xr * sn + xi * c) * scale);
  }
  *(u16x8*)(base + e) = o;
}

// ===== ring-3 deep-pipelined GEMM: 128x256 tile, BK=64, counted vmcnt =====
template <int EPI>
__global__ __launch_bounds__(512, 1) void gemm3r(
    const u16* __restrict__ A, const u16* __restrict__ Bt, float* __restrict__ Cf,
    u16* __restrict__ Qo, u16* __restrict__ Ko, u16* __restrict__ Vo, int N, int ntn) {
  constexpr int K = 2048, NT = K / 64;
  constexpr int BSZ = (128 + 256) * 64;
  __shared__ __align__(16) u16 lds[3][BSZ];

  const int t = threadIdx.x;
  const int l = t & 63, lh = l >> 4, ll = l & 15;
  const int w = t >> 6, wm = w >> 2, wn = w & 3;

  const int bid = blockIdx.x;
  const int swz = (bid & 7) * (gridDim.x >> 3) + (bid >> 3);
  const int tm = swz / ntn, tn = swz % ntn;

  const u16* Ab = A + (size_t)tm * 128 * K;
  const u16* Bb = Bt + (size_t)tn * 256 * K;

  const int sr = t >> 3;
  const int sc8 = ((t & 7) ^ (sr & 7)) * 8;

  f32x4 acc[4][4] = {};

  auto STAGE = [&](int tau) {
    const int kt = tau * 64;
    u16* buf = &lds[tau % 3][0];
#pragma unroll
    for (int c = 0; c < 2; ++c)
      gl_lds16(Ab + (size_t)(c * 64 + sr) * K + kt + sc8, buf + c * 4096 + t * 8);
#pragma unroll
    for (int c = 0; c < 4; ++c)
      gl_lds16(Bb + (size_t)(c * 64 + sr) * K + kt + sc8,
               buf + 8192 + c * 4096 + t * 8);
  };

  STAGE(0);
  STAGE(1);
  __builtin_amdgcn_s_waitcnt(0xF70 | 6);
  __builtin_amdgcn_s_barrier();
  asm volatile("" ::: "memory");

  for (int tt = 0; tt < NT; ++tt) {
    if (tt + 2 < NT) STAGE(tt + 2);
    const u16* bufA = &lds[tt % 3][0];
    const u16* bufB = bufA + 8192;
#pragma unroll
    for (int kk = 0; kk < 2; ++kk) {
      const int cb = ((kk * 4 + lh) ^ (ll & 7)) * 8;
      bf16x8 af[4], bv[4];
#pragma unroll
      for (int m = 0; m < 4; ++m)
        af[m] = *(const bf16x8*)(bufA + (wm * 64 + m * 16 + ll) * 64 + cb);
#pragma unroll
      for (int n = 0; n < 4; ++n)
        bv[n] = *(const bf16x8*)(bufB + (wn * 64 + n * 16 + ll) * 64 + cb);
      __builtin_amdgcn_s_setprio(1);
#pragma unroll
      for (int m = 0; m < 4; ++m)
#pragma unroll
        for (int n = 0; n < 4; ++n)
          acc[m][n] =
              __builtin_amdgcn_mfma_f32_16x16x32_bf16(af[m], bv[n], acc[m][n], 0, 0, 0);
      __builtin_amdgcn_s_setprio(0);
    }
    if (tt + 1 < NT) {
      if (tt + 2 < NT)
        __builtin_amdgcn_s_waitcnt(0xF70 | 6);
      else
        __builtin_amdgcn_s_waitcnt(0xF70);
      __builtin_amdgcn_s_barrier();
      asm volatile("" ::: "memory");
    }
  }

#pragma unroll
  for (int m = 0; m < 4; ++m)
#pragma unroll
    for (int n = 0; n < 4; ++n)
#pragma unroll
      for (int j = 0; j < 4; ++j) {
        int row = tm * 128 + wm * 64 + m * 16 + lh * 4 + j;
        int col = tn * 256 + wn * 64 + n * 16 + ll;
        if constexpr (EPI == 0) {
          Cf[(size_t)row * N + col] = acc[m][n][j];
        } else {
          int b = row >> 11, s = row & (S_LEN - 1);
          u16 val = f2bf(acc[m][n][j]);
          int d = col & 127;
          if (col < 2048) {
            int hh = col >> 7;
            Qo[(((size_t)b * NHEAD + hh) * S_LEN + s) * HD + d] = val;
          } else if (col < 3072) {
            int kh = (col >> 7) & 7;
            Ko[(((size_t)b * NKV + kh) * S_LEN + s) * HD + d] = val;
          } else {
            int kh = (col >> 7) & 7;
            Vo[(((size_t)b * NKV + kh) * S_LEN + s) * HD + d] = val;
          }
        }
      }
}

// ---- V [bkv][2048][128] -> Vt [bkv][128][2048] (LDS tiled transpose) ----
__global__ __launch_bounds__(256) void transpose_v(const u16* __restrict__ V,
                                                   u16* __restrict__ Vt) {
  __shared__ u16 tile[64][72];
  int id = blockIdx.x;
  int bkv = id >> 6;
  int dt = (id >> 5) & 1;
  int st = id & 31;
  const u16* Vb = V + (size_t)bkv * S_LEN * HD;
  u16* Vo = Vt + (size_t)bkv * HD * S_LEN;
  int r = threadIdx.x >> 3, c8 = (threadIdx.x & 7) * 8;
#pragma unroll
  for (int it = 0; it < 2; ++it) {
    int rr = it * 32 + r;
    *(u16x8*)(&tile[rr][c8]) =
        *(const u16x8*)(Vb + (size_t)(st * 64 + rr) * HD + dt * 64 + c8);
  }
  __syncthreads();
#pragma unroll
  for (int it = 0; it < 2; ++it) {
    int rr = it * 32 + r;
    u16x8 o;
#pragma unroll
    for (int j = 0; j < 8; ++j) o[j] = tile[c8 + j][rr];
    *(u16x8*)(Vo + (size_t)(dt * 64 + rr) * S_LEN + st * 64 + c8) = o;
  }
}

// ======= causal GQA flash attention: 8 waves, in-block KV split =======
// waves 0-3 (half 0): even KV tiles; waves 4-7 (half 1): odd KV tiles.
// Per-half unpadded XOR-swizzled K/V LDS (conflict-light b128 reads).
// Flash-merge of the two halves through LDS at the end; half 0 writes O.
// NOTE: 2nd launch_bounds arg = min blocks/CU (CUDA semantics): 2 blocks
// x 8 waves = 4 waves/SIMD -> 128-VGPR budget. (512,4) forced 64 VGPR and
// spilled ~500 MB/dispatch to scratch — round-6 regression.
__global__ __launch_bounds__(512, 2) void attn_fwd(const u16* __restrict__ Q,
                                                   const u16* __restrict__ Kh,
                                                   const u16* __restrict__ Vt,
                                                   u16* __restrict__ O) {
  __shared__ __align__(16) u16 SH[40960];  // 80 KB

  const int t = threadIdx.x;
  const int w = t >> 6, l = t & 63, lh = l >> 4, ll = l & 15;
  const int qg = w & 3, half = w >> 2;
  const int t256 = t & 255;

  const int bid = blockIdx.x;
  const int swzb = (bid & 7) * 64 + (bid >> 3);
  const int bh = swzb >> 4;
  const int pair = swzb & 15;
  const int b = bh >> 4, h = bh & 15;
  const int bkv = b * NKV + (h >> 1);

  const u16* Qb = Q + (size_t)bh * S_LEN * HD;
  const u16* Kb = Kh + (size_t)bkv * S_LEN * HD;
  const u16* Vb = Vt + (size_t)bkv * HD * S_LEN;

  u16* KS = SH + half * 8192;           // [64 rows][128 u16] swizzled
  u16* VS = SH + 16384 + half * 8192;   // [128 rows][64 u16] swizzled
  u16* PW = SH + 32768 + w * 1024;      // per-wave P tile
  float* CmbO = (float*)SH;             // [4][16][128] f32 (aliases KS)
  float* CmbML = (float*)(SH + 16384);  // [4][2][16] f32 (aliases VS)

  const int krow = t256 >> 4;            // 0..15
  const int ksHi = t256 & 8, ksLo = t256 & 7;
  const int vrow = t256 >> 3;            // 0..31
  const int vsLo = t256 & 7;

  u16x8 krg[4], vrg[4];
  auto loadK = [&](int tile) {
    const int kv0 = tile * 64;
#pragma unroll
    for (int p = 0; p < 4; ++p) {
      int r = p * 16 + krow;
      int s = ksHi | (ksLo ^ (r & 7));  // pre-permuted source slot
      krg[p] = *(const u16x8*)(Kb + (size_t)(kv0 + r) * HD + s * 8);
    }
  };
  auto loadV = [&](int tile) {
    const int kv0 = tile * 64;
#pragma unroll
    for (int i = 0; i < 4; ++i) {
      int d = i * 32 + vrow;
      int s = vsLo ^ (d & 7);
      vrg[i] = *(const u16x8*)(Vb + (size_t)d * S_LEN + kv0 + s * 8);
    }
  };
  auto storeKV = [&]() {  // LDS writes linear in lane -> conflict-free
#pragma unroll
    for (int p = 0; p < 4; ++p)
      *(u16x8*)(KS + (p * 16 + krow) * 128 + (t256 & 15) * 8) = krg[p];
#pragma unroll
    for (int i = 0; i < 4; ++i)
      *(u16x8*)(VS + (i * 32 + vrow) * 64 + vsLo * 8) = vrg[i];
  };

  const bf16x8 vones = {0x3F80, 0x3F80, 0x3F80, 0x3F80, 0x3F80, 0x3F80, 0x3F80, 0x3F80};

  for (int hf = 0; hf < 2; ++hf) {
    const int qt = hf ? (31 - pair) : pair;
    const int q0 = qt * 64;

    bf16x8 qf[4];
#pragma unroll
    for (int c = 0; c < 4; ++c)
      qf[c] = *(const bf16x8*)(Qb + (size_t)(q0 + qg * 16 + ll) * HD + c * 32 + lh * 8);

    f32x4 accO[8] = {};
    f32x4 accL = {0.f, 0.f, 0.f, 0.f};
    float mrow[4] = {-1e30f, -1e30f, -1e30f, -1e30f};

    const int nt = qt + 1;
    const int nt2 = (nt + 1) >> 1;
    int ti = half;
    if (ti < nt) {
      loadK(ti);
      loadV(ti);
    }
    __syncthreads();  // also protects CmbO readers of previous hf
    if (ti < nt) storeKV();
    __syncthreads();

    for (int i = 0; i < nt2; ++i) {
      const int tin = ti + 2;
      const bool act = ti < nt;    // wave-uniform
      const bool actn = tin < nt;  // wave-uniform
      if (actn) loadK(tin);

      f32x4 sf[4];
      if (act) {
#pragma unroll
        for (int f = 0; f < 4; ++f) {
          sf[f] = f32x4{0.f, 0.f, 0.f, 0.f};
#pragma unroll
          for (int c = 0; c < 4; ++c) {
            const int slot = c * 4 + lh;
            const int eff = (slot & 8) | ((slot & 7) ^ (ll & 7));
            bf16x8 kf = *(const bf16x8*)(KS + (f * 16 + ll) * 128 + eff * 8);
            sf[f] = __builtin_amdgcn_mfma_f32_16x16x32_bf16(qf[c], kf, sf[f], 0, 0, 0);
          }
        }
        if (ti == nt - 1) {  // diagonal tile: causal mask
          const int kv0 = ti * 64;
#pragma unroll
          for (int f = 0; f < 4; ++f)
#pragma unroll
            for (int j = 0; j < 4; ++j) {
              int kvg = kv0 + f * 16 + ll;
              int qgl = q0 + qg * 16 + lh * 4 + j;
              if (kvg > qgl) sf[f][j] = -1e30f;
            }
        }
      }
      if (actn) loadV(tin);
      if (act) {
        float corr[4];
#pragma unroll
        for (int j = 0; j < 4; ++j) {
          float mx = fmaxf(fmaxf(sf[0][j], sf[1][j]), fmaxf(sf[2][j], sf[3][j]));
          mx = redmax16(mx);
          float mnew = fmaxf(mrow[j], mx);
          corr[j] = __builtin_amdgcn_exp2f(mrow[j] - mnew);
          mrow[j] = mnew;
#pragma unroll
          for (int f = 0; f < 4; ++f) sf[f][j] = __builtin_amdgcn_exp2f(sf[f][j] - mnew);
        }
#pragma unroll
        for (int n = 0; n < 8; ++n)
#pragma unroll
          for (int j = 0; j < 4; ++j) accO[n][j] *= corr[j];
#pragma unroll
        for (int j = 0; j < 4; ++j) accL[j] *= corr[j];

        char* Pw = (char*)PW;
#pragma unroll
        for (int f = 0; f < 4; ++f)
#pragma unroll
          for (int j = 0; j < 4; ++j) {
            int rr = lh * 4 + j, cc = f * 16 + ll;
            unsigned bo = (unsigned)(rr * 128 + cc * 2) ^ (unsigned)((rr & 7) << 4);
            *(u16*)(Pw + bo) = f2bf(sf[f][j]);
          }

#pragma unroll
        for (int kc = 0; kc < 2; ++kc) {
          unsigned bo =
              (unsigned)(ll * 128 + (kc * 32 + lh * 8) * 2) ^ (unsigned)((ll & 7) << 4);
          bf16x8 pf = *(const bf16x8*)(Pw + bo);
#pragma unroll
          for (int n = 0; n < 8; ++n) {
            const int eff = (kc * 4 + lh) ^ (ll & 7);
            bf16x8 vf = *(const bf16x8*)(VS + (n * 16 + ll) * 64 + eff * 8);
            accO[n] = __builtin_amdgcn_mfma_f32_16x16x32_bf16(pf, vf, accO[n], 0, 0, 0);
          }
          accL = __builtin_amdgcn_mfma_f32_16x16x32_bf16(pf, vones, accL, 0, 0, 0);
        }
      }
      __syncthreads();
      if (actn) storeKV();
      __syncthreads();
      ti = tin;
    }

    // ---- flash-merge of the two halves ----
    if (half == 1) {
#pragma unroll
      for (int n = 0; n < 8; ++n)
#pragma unroll
        for (int j = 0; j < 4; ++j)
          CmbO[(qg * 16 + lh * 4 + j) * 128 + n * 16 + ll] = accO[n][j];
      if (ll == 0) {
#pragma unroll
        for (int j = 0; j < 4; ++j) {
          CmbML[qg * 32 + lh * 4 + j] = mrow[j];
          CmbML[qg * 32 + 16 + lh * 4 + j] = accL[j];
        }
      }
    }
    __syncthreads();
    if (half == 0) {
      float aa[4], bb[4], inv[4];
#pragma unroll
      for (int j = 0; j < 4; ++j) {
        float m2 = CmbML[qg * 32 + lh * 4 + j];
        float l2 = CmbML[qg * 32 + 16 + lh * 4 + j];
        float mf = fmaxf(mrow[j], m2);
        aa[j] = __builtin_amdgcn_exp2f(mrow[j] - mf);
        bb[j] = __builtin_amdgcn_exp2f(m2 - mf);
        inv[j] = 1.0f / (accL[j] * aa[j] + l2 * bb[j]);
      }
      const size_t orow = (size_t)(b * S_LEN + q0 + qg * 16 + lh * 4) * 2048 + h * HD;
#pragma unroll
      for (int n = 0; n < 8; ++n)
#pragma unroll
        for (int j = 0; j < 4; ++j) {
          float o2 = CmbO[(qg * 16 + lh * 4 + j) * 128 + n * 16 + ll];
          O[orow + (size_t)j * 2048 + n * 16 + ll] =
              f2bf((accO[n][j] * aa[j] + o2 * bb[j]) * inv[j]);
        }
    }
  }
}

extern "C" void kernel_launch(void* const* d_in, const int* in_sizes, int n_in,
                              void* d_out, int out_size, void* d_ws, size_t ws_size,
                              hipStream_t stream) {
  (void)in_sizes;
  (void)n_in;
  (void)out_size;
  (void)ws_size;
  const float* x = (const float*)d_in[0];
  const float* fc = (const float*)d_in[1];
  const float* fs = (const float*)d_in[2];
  const float* wq = (const float*)d_in[3];
  const float* wk = (const float*)d_in[4];
  const float* wv = (const float*)d_in[5];
  const float* wo = (const float*)d_in[6];
  float* out = (float*)d_out;

  char* ws = (char*)d_ws;
  u16* wcatT = (u16*)ws;             // [4096][2048] bf16  16.78 MB (dead after gemm<1>)
  u16* vtb = (u16*)ws;               // aliases wcatT: [16][128][2048]  8.39 MB
  u16* woT = (u16*)(ws + 16777216);  // [2048][2048]        8.39 MB
  u16* xo = (u16*)(ws + 25165824);   // x_bf16 then O      16.78 MB
  u16* qb = (u16*)(ws + 41943040);   // [32][2048][128]    16.78 MB
  u16* kb = (u16*)(ws + 58720256);   // [16][2048][128]     8.39 MB
  u16* vb = (u16*)(ws + 67108864);   // [16][2048][128]     8.39 MB
  // total 75,497,472 bytes

  conv_bf16<<<8192, 256, 0, stream>>>(x, xo, 2097152);
  transpose_w4<<<3072, 256, 0, stream>>>(wq, wk, wv, wo, wcatT, woT);

  gemm3r<1><<<512, 512, 0, stream>>>(xo, wcatT, nullptr, qb, kb, vb, 4096, 16);
  transpose_v<<<1024, 256, 0, stream>>>(vb, vtb);
  rope_qk<<<6144, 256, 0, stream>>>(qb, kb, fc, fs);
  attn_fwd<<<512, 512, 0, stream>>>(qb, kb, vtb, xo);
  gemm3r<0><<<256, 512, 0, stream>>>(xo, woT, out, nullptr, nullptr, nullptr, 2048, 8);
}

// Round 8
// 212.254 us; speedup vs baseline: 1.5522x; 1.1033x over previous
//
#include <hip/hip_runtime.h>

typedef unsigned short u16;
typedef short bf16x8 __attribute__((ext_vector_type(8)));
typedef float f32x4 __attribute__((ext_vector_type(4)));
typedef float f32x16 __attribute__((ext_vector_type(16)));
typedef int i32x2 __attribute__((ext_vector_type(2)));
typedef unsigned int u32x4 __attribute__((ext_vector_type(4)));
typedef unsigned short u16x4 __attribute__((ext_vector_type(4)));
typedef unsigned short u16x8 __attribute__((ext_vector_type(8)));

#define S_LEN 2048
#define NHEAD 16
#define NKV 8
#define HD 128

__device__ __forceinline__ u16 f2bf(float f) {
  unsigned u = __builtin_bit_cast(unsigned, f);
  u = (u + 0x7FFFu + ((u >> 16) & 1u)) >> 16;
  return (u16)u;
}
__device__ __forceinline__ float bf2f(u16 h) {
  unsigned u = ((unsigned)h) << 16;
  return __builtin_bit_cast(float, u);
}

__device__ __forceinline__ void gl_lds16(const void* g, void* l) {
  __builtin_amdgcn_global_load_lds(
      (const __attribute__((address_space(1))) unsigned int*)g,
      (__attribute__((address_space(3))) unsigned int*)l, 16, 0, 0);
}

__device__ __forceinline__ unsigned cvtpk_bf16(float a, float b) {
  unsigned r;
  asm("v_cvt_pk_bf16_f32 %0, %1, %2" : "=v"(r) : "v"(a), "v"(b));
  return r;
}

// ---------------- elementwise f32 -> bf16 ----------------
__global__ __launch_bounds__(256) void conv_bf16(const float* __restrict__ in,
                                                 u16* __restrict__ out, int n4) {
  int i = blockIdx.x * 256 + threadIdx.x;
  if (i >= n4) return;
  f32x4 v = *(const f32x4*)(in + (size_t)i * 4);
  u16x4 o;
#pragma unroll
  for (int j = 0; j < 4; ++j) o[j] = f2bf(v[j]);
  *(u16x4*)(out + (size_t)i * 4) = o;
}

// ---- fused transpose of wq/wk/wv/wo: f32 [K][N] -> bf16 [roff+n][2048] ----
__global__ __launch_bounds__(256) void transpose_w4(
    const float* __restrict__ wq, const float* __restrict__ wk,
    const float* __restrict__ wv, const float* __restrict__ wo,
    u16* __restrict__ wcatT, u16* __restrict__ woT) {
  __shared__ float tile[64][65];
  int id = blockIdx.x;
  const float* in;
  u16* out;
  int N, roff, nx;
  if (id < 1024) {
    in = wq; out = wcatT; N = 2048; roff = 0; nx = 32;
  } else if (id < 1536) {
    in = wk; out = wcatT; N = 1024; roff = 2048; nx = 16; id -= 1024;
  } else if (id < 2048) {
    in = wv; out = wcatT; N = 1024; roff = 3072; nx = 16; id -= 1536;
  } else {
    in = wo; out = woT; N = 2048; roff = 0; nx = 32; id -= 2048;
  }
  int bx = id % nx;
  int by = id / nx;
  int k0 = by * 64, n0 = bx * 64;
  int tx = threadIdx.x & 63, ty = threadIdx.x >> 6;
#pragma unroll
  for (int p = 0; p < 16; ++p) {
    int r = p * 4 + ty;
    tile[r][tx] = in[(size_t)(k0 + r) * N + n0 + tx];
  }
  __syncthreads();
#pragma unroll
  for (int p = 0; p < 16; ++p) {
    int r = p * 4 + ty;
    out[(size_t)(roff + n0 + r) * 2048 + k0 + tx] = f2bf(tile[tx][r]);
  }
}

// ---------------- RoPE in-place on Q (scaled) and K ----------------
__global__ __launch_bounds__(256) void rope_qk(u16* __restrict__ q, u16* __restrict__ k,
                                               const float* __restrict__ fc,
                                               const float* __restrict__ fs) {
  const int QC = 2 * NHEAD * S_LEN * HD / 8;
  const int KC = 2 * NKV * S_LEN * HD / 8;
  int i = blockIdx.x * 256 + threadIdx.x;
  if (i >= QC + KC) return;
  u16* base;
  float scale;
  size_t e;
  if (i < QC) {
    base = q;
    e = (size_t)i * 8;
    scale = 0.12751744540368598f;  // log2(e)/sqrt(128)
  } else {
    base = k;
    e = (size_t)(i - QC) * 8;
    scale = 1.0f;
  }
  int d8 = (int)(e & 127);
  int s = (int)((e >> 7) & (S_LEN - 1));
  int dp0 = d8 >> 1;
  u16x8 v = *(const u16x8*)(base + e);
  u16x8 o;
#pragma unroll
  for (int p = 0; p < 4; ++p) {
    float xr = bf2f(v[2 * p]), xi = bf2f(v[2 * p + 1]);
    float c = fc[s * 64 + dp0 + p], sn = fs[s * 64 + dp0 + p];
    o[2 * p] = f2bf((xr * c - xi * sn) * scale);
    o[2 * p + 1] = f2bf((xr * sn + xi * c) * scale);
  }
  *(u16x8*)(base + e) = o;
}

// ===== ring-3 deep-pipelined GEMM: 128x256 tile, BK=64, counted vmcnt =====
template <int EPI>
__global__ __launch_bounds__(512, 1) void gemm3r(
    const u16* __restrict__ A, const u16* __restrict__ Bt, float* __restrict__ Cf,
    u16* __restrict__ Qo, u16* __restrict__ Ko, u16* __restrict__ Vo, int N, int ntn) {
  constexpr int K = 2048, NT = K / 64;
  constexpr int BSZ = (128 + 256) * 64;
  __shared__ __align__(16) u16 lds[3][BSZ];

  const int t = threadIdx.x;
  const int l = t & 63, lh = l >> 4, ll = l & 15;
  const int w = t >> 6, wm = w >> 2, wn = w & 3;

  const int bid = blockIdx.x;
  const int swz = (bid & 7) * (gridDim.x >> 3) + (bid >> 3);
  const int tm = swz / ntn, tn = swz % ntn;

  const u16* Ab = A + (size_t)tm * 128 * K;
  const u16* Bb = Bt + (size_t)tn * 256 * K;

  const int sr = t >> 3;
  const int sc8 = ((t & 7) ^ (sr & 7)) * 8;

  f32x4 acc[4][4] = {};

  auto STAGE = [&](int tau) {
    const int kt = tau * 64;
    u16* buf = &lds[tau % 3][0];
#pragma unroll
    for (int c = 0; c < 2; ++c)
      gl_lds16(Ab + (size_t)(c * 64 + sr) * K + kt + sc8, buf + c * 4096 + t * 8);
#pragma unroll
    for (int c = 0; c < 4; ++c)
      gl_lds16(Bb + (size_t)(c * 64 + sr) * K + kt + sc8,
               buf + 8192 + c * 4096 + t * 8);
  };

  STAGE(0);
  STAGE(1);
  __builtin_amdgcn_s_waitcnt(0xF70 | 6);
  __builtin_amdgcn_s_barrier();
  asm volatile("" ::: "memory");

  for (int tt = 0; tt < NT; ++tt) {
    if (tt + 2 < NT) STAGE(tt + 2);
    const u16* bufA = &lds[tt % 3][0];
    const u16* bufB = bufA + 8192;
#pragma unroll
    for (int kk = 0; kk < 2; ++kk) {
      const int cb = ((kk * 4 + lh) ^ (ll & 7)) * 8;
      bf16x8 af[4], bv[4];
#pragma unroll
      for (int m = 0; m < 4; ++m)
        af[m] = *(const bf16x8*)(bufA + (wm * 64 + m * 16 + ll) * 64 + cb);
#pragma unroll
      for (int n = 0; n < 4; ++n)
        bv[n] = *(const bf16x8*)(bufB + (wn * 64 + n * 16 + ll) * 64 + cb);
      __builtin_amdgcn_s_setprio(1);
#pragma unroll
      for (int m = 0; m < 4; ++m)
#pragma unroll
        for (int n = 0; n < 4; ++n)
          acc[m][n] =
              __builtin_amdgcn_mfma_f32_16x16x32_bf16(af[m], bv[n], acc[m][n], 0, 0, 0);
      __builtin_amdgcn_s_setprio(0);
    }
    if (tt + 1 < NT) {
      if (tt + 2 < NT)
        __builtin_amdgcn_s_waitcnt(0xF70 | 6);
      else
        __builtin_amdgcn_s_waitcnt(0xF70);
      __builtin_amdgcn_s_barrier();
      asm volatile("" ::: "memory");
    }
  }

#pragma unroll
  for (int m = 0; m < 4; ++m)
#pragma unroll
    for (int n = 0; n < 4; ++n)
#pragma unroll
      for (int j = 0; j < 4; ++j) {
        int row = tm * 128 + wm * 64 + m * 16 + lh * 4 + j;
        int col = tn * 256 + wn * 64 + n * 16 + ll;
        if constexpr (EPI == 0) {
          Cf[(size_t)row * N + col] = acc[m][n][j];
        } else {
          int b = row >> 11, s = row & (S_LEN - 1);
          u16 val = f2bf(acc[m][n][j]);
          int d = col & 127;
          if (col < 2048) {
            int hh = col >> 7;
            Qo[(((size_t)b * NHEAD + hh) * S_LEN + s) * HD + d] = val;
          } else if (col < 3072) {
            int kh = (col >> 7) & 7;
            Ko[(((size_t)b * NKV + kh) * S_LEN + s) * HD + d] = val;
          } else {
            int kh = (col >> 7) & 7;
            Vo[(((size_t)b * NKV + kh) * S_LEN + s) * HD + d] = val;
          }
        }
      }
}

// ---- V [bkv][2048][128] -> Vt [bkv][128][2048] (LDS tiled transpose) ----
__global__ __launch_bounds__(256) void transpose_v(const u16* __restrict__ V,
                                                   u16* __restrict__ Vt) {
  __shared__ u16 tile[64][72];
  int id = blockIdx.x;
  int bkv = id >> 6;
  int dt = (id >> 5) & 1;
  int st = id & 31;
  const u16* Vb = V + (size_t)bkv * S_LEN * HD;
  u16* Vo = Vt + (size_t)bkv * HD * S_LEN;
  int r = threadIdx.x >> 3, c8 = (threadIdx.x & 7) * 8;
#pragma unroll
  for (int it = 0; it < 2; ++it) {
    int rr = it * 32 + r;
    *(u16x8*)(&tile[rr][c8]) =
        *(const u16x8*)(Vb + (size_t)(st * 64 + rr) * HD + dt * 64 + c8);
  }
  __syncthreads();
#pragma unroll
  for (int it = 0; it < 2; ++it) {
    int rr = it * 32 + r;
    u16x8 o;
#pragma unroll
    for (int j = 0; j < 8; ++j) o[j] = tile[c8 + j][rr];
    *(u16x8*)(Vo + (size_t)(dt * 64 + rr) * S_LEN + st * 64 + c8) = o;
  }
}

// ======= causal GQA flash attention: 32x32 MFMA, swapped QK^T, =======
// ======= in-register softmax (cvt_pk + permlane32_swap), no P-LDS =======
// 4 waves x 32 q-rows = 128-row q-tile per block; KVBLK=64 double-buffered.
// Grid = 32 bh x 16 qt, qt DESCENDING (LPT balance). 64KB LDS -> 2 blk/CU.
__global__ __launch_bounds__(256, 2) void attn_fwd(const u16* __restrict__ Q,
                                                   const u16* __restrict__ Kh,
                                                   const u16* __restrict__ Vt,
                                                   u16* __restrict__ O) {
  __shared__ __align__(16) u16 KS[2][64 * 128];   // [kv 64][16 slots x 8] swizzled
  __shared__ __align__(16) u16 VS[2][128 * 64];   // [d 128][8 slots x 8] swizzled

  const int t = threadIdx.x;
  const int l = t & 63, hi = l >> 5, ll = l & 31;
  const int wq = t >> 6;

  const int bid = blockIdx.x;
  const int qt = 15 - (bid >> 5);  // big tiles dispatched first (LPT)
  const int bh = bid & 31;
  const int b = bh >> 4, h = bh & 15;
  const int bkv = b * NKV + (h >> 1);

  const u16* Qb = Q + (size_t)bh * S_LEN * HD;
  const u16* Kb = Kh + (size_t)bkv * S_LEN * HD;
  const u16* Vb = Vt + (size_t)bkv * HD * S_LEN;

  const int q0w = qt * 128 + wq * 32;
  const int qg = q0w + ll;  // this lane's q row (S^T col)

  // Q as B-operand frags: qf[c] = Q[qg][c*16 + hi*8 .. +7]
  bf16x8 qf[8];
#pragma unroll
  for (int c = 0; c < 8; ++c)
    qf[c] = *(const bf16x8*)(Qb + (size_t)qg * HD + c * 16 + hi * 8);

  // staging (256 thr): K 4 chunks of 16 rows; V 4 chunks of 32 d-rows
  const int krow = t >> 4, kslot = t & 15;
  const int vrow = t >> 3, vslot = t & 7;
  u16x8 krg[4], vrg[4];

  auto loadKV = [&](int tile) {
    const int kv0 = tile * 64;
#pragma unroll
    for (int c = 0; c < 4; ++c) {
      int r = c * 16 + krow;
      int sg = (kslot & 8) | ((kslot & 7) ^ (r & 7));  // inverse-swizzled source
      krg[c] = *(const u16x8*)(Kb + (size_t)(kv0 + r) * HD + sg * 8);
    }
#pragma unroll
    for (int c = 0; c < 4; ++c) {
      int d = c * 32 + vrow;
      int sg = vslot ^ (d & 7);
      vrg[c] = *(const u16x8*)(Vb + (size_t)d * S_LEN + kv0 + sg * 8);
    }
  };
  auto storeKV = [&](int bi) {  // linear-in-lane LDS writes
#pragma unroll
    for (int c = 0; c < 4; ++c)
      *(u16x8*)(&KS[bi][(c * 16 + krow) * 128 + kslot * 8]) = krg[c];
#pragma unroll
    for (int c = 0; c < 4; ++c)
      *(u16x8*)(&VS[bi][(c * 32 + vrow) * 64 + vslot * 8]) = vrg[c];
  };

  f32x16 accO[4] = {};  // O[32q][128d]: 4 d-blocks of 32
  float m = -1e30f, lsum = 0.f;

  const int nt = 2 * qt + 2;
  loadKV(0);
  storeKV(0);
  __syncthreads();

  for (int tt = 0; tt < nt; ++tt) {
    const int kv0 = tt * 64;
    const bool actn = (tt + 1 < nt);
    if (actn) loadKV(tt + 1);  // issue early; consumed after barrier (T14)

    if (kv0 <= q0w + 31) {  // wave-uniform: skip fully-masked tiles
      const u16* ks = &KS[tt & 1][0];
      const u16* vs = &VS[tt & 1][0];

      // ---- S^T = K x Q  (64kv x 32q), col = q = ll, row = kv frag ----
      f32x16 st[2] = {};
      __builtin_amdgcn_s_setprio(1);
#pragma unroll
      for (int c = 0; c < 8; ++c) {
        int slot = 2 * c + hi;
        int eff = (slot & 8) | ((slot & 7) ^ (ll & 7));
        bf16x8 kf0 = *(const bf16x8*)(ks + (size_t)ll * 128 + eff * 8);
        st[0] = __builtin_amdgcn_mfma_f32_32x32x16_bf16(kf0, qf[c], st[0], 0, 0, 0);
        bf16x8 kf1 = *(const bf16x8*)(ks + (size_t)(32 + ll) * 128 + eff * 8);
        st[1] = __builtin_amdgcn_mfma_f32_32x32x16_bf16(kf1, qf[c], st[1], 0, 0, 0);
      }
      __builtin_amdgcn_s_setprio(0);

      // ---- causal mask (diagonal region only) ----
      if (kv0 + 63 > q0w) {
#pragma unroll
        for (int f = 0; f < 2; ++f)
#pragma unroll
          for (int r = 0; r < 16; ++r) {
            int kvg = kv0 + f * 32 + (r & 3) + 8 * (r >> 2) + 4 * hi;
            if (kvg > qg) st[f][r] = -1e30f;
          }
      }

      // ---- row max (lane-local tree + one half-swap) ----
      float a[16];
#pragma unroll
      for (int i = 0; i < 16; ++i) a[i] = fmaxf(st[0][i], st[1][i]);
#pragma unroll
      for (int s = 8; s >= 1; s >>= 1)
#pragma unroll
        for (int i = 0; i < 8; ++i)
          if (i < s) a[i] = fmaxf(a[i], a[i + s]);
      float pmax = fmaxf(a[0], __shfl_xor(a[0], 32));

      if (tt == 0) {
        m = pmax;
      } else if (!__all(pmax <= m + 8.0f)) {  // defer-max: rescale rare
        float mnew = fmaxf(m, pmax);
        float corr = __builtin_amdgcn_exp2f(m - mnew);
        m = mnew;
        lsum *= corr;
        int ci = __builtin_bit_cast(int, corr);
#pragma unroll
        for (int reg = 0; reg < 16; ++reg) {
          int row = (reg & 3) + 8 * (reg >> 2) + 4 * hi;
          float cq = __builtin_bit_cast(
              float, __builtin_amdgcn_ds_bpermute(row << 2, ci));
#pragma unroll
          for (int dblk = 0; dblk < 4; ++dblk) accO[dblk][reg] *= cq;
        }
      }

      // ---- P = exp2(S - m); local row-sum ----
#pragma unroll
      for (int f = 0; f < 2; ++f)
#pragma unroll
        for (int r = 0; r < 16; ++r)
          st[f][r] = __builtin_amdgcn_exp2f(st[f][r] - m);
      float s1[16];
#pragma unroll
      for (int i = 0; i < 16; ++i) s1[i] = st[0][i] + st[1][i];
#pragma unroll
      for (int s = 8; s >= 1; s >>= 1)
#pragma unroll
        for (int i = 0; i < 8; ++i)
          if (i < s) s1[i] += s1[i + s];
      lsum += s1[0];

      // ---- pack P to bf16 pairs: pk[bg][ap], bg = kv>>3 (global b) ----
      unsigned pk[8][2];
#pragma unroll
      for (int bg = 0; bg < 8; ++bg)
#pragma unroll
        for (int ap = 0; ap < 2; ++ap)
          pk[bg][ap] = cvtpk_bf16(st[bg >> 2][(bg & 3) * 4 + 2 * ap],
                                  st[bg >> 2][(bg & 3) * 4 + 2 * ap + 1]);

      // ---- PV: A-frag via permlane32_swap (2 per kc), B = V from LDS ----
      __builtin_amdgcn_s_setprio(1);
#pragma unroll
      for (int kc = 0; kc < 4; ++kc) {
        i32x2 sa = __builtin_amdgcn_permlane32_swap(
            (int)pk[2 * kc][0], (int)pk[2 * kc + 1][0], false, false);
        i32x2 sb = __builtin_amdgcn_permlane32_swap(
            (int)pk[2 * kc][1], (int)pk[2 * kc + 1][1], false, false);
        union {
          unsigned u[4];
          bf16x8 v;
        } pa;
        pa.u[0] = (unsigned)sa[0];
        pa.u[1] = (unsigned)sb[0];
        pa.u[2] = (unsigned)sa[1];
        pa.u[3] = (unsigned)sb[1];
        int eff = (2 * kc + hi) ^ (ll & 7);
#pragma unroll
        for (int dblk = 0; dblk < 4; ++dblk) {
          bf16x8 vf = *(const bf16x8*)(vs + (size_t)(dblk * 32 + ll) * 64 + eff * 8);
          accO[dblk] =
              __builtin_amdgcn_mfma_f32_32x32x16_bf16(pa.v, vf, accO[dblk], 0, 0, 0);
        }
      }
      __builtin_amdgcn_s_setprio(0);
    }

    __syncthreads();
    if (actn) storeKV((tt + 1) & 1);
    __syncthreads();
  }

  // ---- epilogue: combine halves' l, normalize, write ----
  lsum += __shfl_xor(lsum, 32);
  float linv = 1.0f / lsum;
  int li = __builtin_bit_cast(int, linv);
  float inv[16];
#pragma unroll
  for (int reg = 0; reg < 16; ++reg) {
    int row = (reg & 3) + 8 * (reg >> 2) + 4 * hi;
    inv[reg] = __builtin_bit_cast(float, __builtin_amdgcn_ds_bpermute(row << 2, li));
  }
#pragma unroll
  for (int dblk = 0; dblk < 4; ++dblk)
#pragma unroll
    for (int reg = 0; reg < 16; ++reg) {
      int row = (reg & 3) + 8 * (reg >> 2) + 4 * hi;
      O[(size_t)(b * S_LEN + q0w + row) * 2048 + h * HD + dblk * 32 + ll] =
          f2bf(accO[dblk][reg] * inv[reg]);
    }
}

extern "C" void kernel_launch(void* const* d_in, const int* in_sizes, int n_in,
                              void* d_out, int out_size, void* d_ws, size_t ws_size,
                              hipStream_t stream) {
  (void)in_sizes;
  (void)n_in;
  (void)out_size;
  (void)ws_size;
  const float* x = (const float*)d_in[0];
  const float* fc = (const float*)d_in[1];
  const float* fs = (const float*)d_in[2];
  const float* wq = (const float*)d_in[3];
  const float* wk = (const float*)d_in[4];
  const float* wv = (const float*)d_in[5];
  const float* wo = (const float*)d_in[6];
  float* out = (float*)d_out;

  char* ws = (char*)d_ws;
  u16* wcatT = (u16*)ws;             // [4096][2048] bf16  16.78 MB (dead after gemm<1>)
  u16* vtb = (u16*)ws;               // aliases wcatT: [16][128][2048]  8.39 MB
  u16* woT = (u16*)(ws + 16777216);  // [2048][2048]        8.39 MB
  u16* xo = (u16*)(ws + 25165824);   // x_bf16 then O      16.78 MB
  u16* qb = (u16*)(ws + 41943040);   // [32][2048][128]    16.78 MB
  u16* kb = (u16*)(ws + 58720256);   // [16][2048][128]     8.39 MB
  u16* vb = (u16*)(ws + 67108864);   // [16][2048][128]     8.39 MB
  // total 75,497,472 bytes

  conv_bf16<<<8192, 256, 0, stream>>>(x, xo, 2097152);
  transpose_w4<<<3072, 256, 0, stream>>>(wq, wk, wv, wo, wcatT, woT);

  gemm3r<1><<<512, 512, 0, stream>>>(xo, wcatT, nullptr, qb, kb, vb, 4096, 16);
  transpose_v<<<1024, 256, 0, stream>>>(vb, vtb);
  rope_qk<<<6144, 256, 0, stream>>>(qb, kb, fc, fs);
  attn_fwd<<<512, 256, 0, stream>>>(qb, kb, vtb, xo);
  gemm3r<0><<<256, 512, 0, stream>>>(xo, woT, out, nullptr, nullptr, nullptr, 2048, 8);
}